// Round 6
// baseline (597.740 us; speedup 1.0000x reference)
//
#include <hip/hip_runtime.h>
#include <hip/hip_bf16.h>
#include <cstdint>
#include <cmath>

// Self-attention, B=8 T=1024 H=8 D=512 (hidden 4096), fp32 in/out, bf16 MFMA compute.
// Pipeline GEMMs (QKV-proj, QK^T, PV) on a 256x256/BK=64/8-wave kernel with
// both-sides XOR-swizzled LDS, depth-2 counted-vmcnt prefetch, setprio.
// Out-proj stays on the 128x128 2-phase split-K kernel.

typedef __attribute__((ext_vector_type(8))) short short8;
typedef __attribute__((ext_vector_type(4))) float f32x4;

#define DEVINL __device__ __forceinline__

DEVINL float bf2f(ushort u) { union { uint32_t i; float f; } w; w.i = (uint32_t)u << 16; return w.f; }
DEVINL ushort f2bf(float f) {
  union { float f; uint32_t i; } w; w.f = f;
  uint32_t r = w.i + 0x7FFFu + ((w.i >> 16) & 1u);   // RNE
  return (ushort)(r >> 16);
}

DEVINL void gl_lds16(const ushort* g, ushort* l) {
  __builtin_amdgcn_global_load_lds(
      (const __attribute__((address_space(1))) uint32_t*)g,
      (__attribute__((address_space(3))) uint32_t*)l, 16, 0, 0);
}

// swizzled index into a [32 rows][128 cols] ushort staging tile (old 128^2 kernel epilogue)
DEVINL int csw(int row, int col) {
  return row * 128 + ((((col >> 4) ^ ((row >> 2) & 7)) << 4) | (col & 15));
}

// ---------------- fp32 -> bf16 convert (8 elems/thread), optional scale ----------------
__global__ __launch_bounds__(256) void cvt_f32_bf16(const float* __restrict__ in,
                                                    ushort* __restrict__ out,
                                                    int n8, float scale) {
  int i = blockIdx.x * 256 + threadIdx.x;
  if (i >= n8) return;
  const float4* p = (const float4*)in + (size_t)i * 2;
  float4 a = p[0], b = p[1];
  short8 o;
  o[0] = (short)f2bf(a.x * scale); o[1] = (short)f2bf(a.y * scale);
  o[2] = (short)f2bf(a.z * scale); o[3] = (short)f2bf(a.w * scale);
  o[4] = (short)f2bf(b.x * scale); o[5] = (short)f2bf(b.y * scale);
  o[6] = (short)f2bf(b.z * scale); o[7] = (short)f2bf(b.w * scale);
  ((short8*)out)[i] = o;
}

// ---------------- zero fp32 buffer ----------------
__global__ __launch_bounds__(256) void zerof4(float4* __restrict__ p, int n4) {
  int i = blockIdx.x * 256 + threadIdx.x;
  if (i < n4) p[i] = float4{0.f, 0.f, 0.f, 0.f};
}

// ================= 256x256 / BK=64 / 8-wave bf16 C = A * B^T =================
// A: [M,K] row-major (lda), B: [N,K] row-major (ldb), C bf16 [M,N] (ldc).
// LDS 128 KB: 2 bufs x (A 256x64 | B 256x64), chunk-XOR swizzled (16B chunks,
// chunk' = chunk ^ (row&7)); staged via inverse-swizzled per-lane global source
// (linear global_load_lds dest), read with the same XOR -> conflict-free b128.
// Depth-2 prefetch, s_waitcnt vmcnt(8) (never 0 mid-loop), raw barriers.
// CSKIP: skip blocks above causal diagonal. CKB: kend=(bm+1)*256. ZBH: z=(bi,hi).
template<bool CSKIP, bool CKB, bool ZBH>
__global__ __launch_bounds__(512, 2) void gemm256(
    const ushort* __restrict__ A0, long long sAb, long long sAh,
    const ushort* __restrict__ B0, long long sBb, long long sBh,
    ushort* __restrict__ C0, long long sCb, long long sCh,
    int lda, int ldb, int ldc, int K)
{
  const int bm = blockIdx.x, bn = blockIdx.y, bz = blockIdx.z;
  if (CSKIP && bn > bm) return;
  long long za, zb, zc;
  if (ZBH) {
    const long long bi = bz >> 3, hi = bz & 7;
    za = bi * sAb + hi * sAh; zb = bi * sBb + hi * sBh; zc = bi * sCb + hi * sCh;
  } else {
    za = (long long)bz * sAh; zb = (long long)bz * sBh; zc = (long long)bz * sCh;
  }
  const ushort* A = A0 + za;
  const ushort* B = B0 + zb;
  int kend = K;
  if (CKB) { int kb = (bm + 1) * 256; kend = kb < K ? kb : K; }

  __shared__ ushort smem[65536];           // 128 KB

  const int tid = threadIdx.x;
  const int wid = tid >> 6, lane = tid & 63;
  const int wr = wid >> 2, wc = wid & 3;   // wave grid 2(M) x 4(N); per-wave C = 128x64
  const int l15 = lane & 15, kq = lane >> 4;

  // staging geometry: issue q covers 64 rows; wave covers 8 rows (64 lanes x 16B)
  const int srow = wid * 8 + (lane >> 3);
  const int scol = ((lane & 7) ^ ((lane >> 3) & 7)) * 8;   // inverse-swizzled source chunk
  const ushort* agbase = A + (size_t)(bm * 256 + srow) * lda + scol;
  const ushort* bgbase = B + (size_t)(bn * 256 + srow) * ldb + scol;

  auto STAGE = [&](int buf, int kk) {      // 8 gl_lds issues per thread per K-tile
    ushort* a = &smem[buf * 32768 + wid * 512];
    ushort* b = a + 16384;
#pragma unroll
    for (int q = 0; q < 4; ++q) {
      gl_lds16(agbase + (size_t)q * 64 * lda + kk, a + q * 4096);
      gl_lds16(bgbase + (size_t)q * 64 * ldb + kk, b + q * 4096);
    }
  };

  f32x4 acc[8][4] = {};
  const int nt = kend >> 6;

  STAGE(0, 0);
  for (int t = 0; t < nt; ++t) {
    const int cur = t & 1;
    if (t + 1 < nt) {
      STAGE(cur ^ 1, (t + 1) << 6);
      asm volatile("s_waitcnt vmcnt(8)" ::: "memory");   // tile t done; t+1's 8 in flight
    } else {
      asm volatile("s_waitcnt vmcnt(0)" ::: "memory");   // tail drain
    }
    __builtin_amdgcn_sched_barrier(0);
    __builtin_amdgcn_s_barrier();
    __builtin_amdgcn_sched_barrier(0);

    const ushort* As = &smem[cur * 32768];
    const ushort* Bs = As + 16384;
    short8 bfr[4][2];
#pragma unroll
    for (int n = 0; n < 4; ++n)
#pragma unroll
      for (int ks = 0; ks < 2; ++ks)
        bfr[n][ks] = *(const short8*)
            &Bs[(wc * 64 + n * 16 + l15) * 64 + (((ks * 4 + kq) ^ (l15 & 7)) * 8)];
#pragma unroll
    for (int m = 0; m < 8; ++m) {
      short8 a0 = *(const short8*)
          &As[(wr * 128 + m * 16 + l15) * 64 + (((0 + kq) ^ (l15 & 7)) * 8)];
      short8 a1 = *(const short8*)
          &As[(wr * 128 + m * 16 + l15) * 64 + (((4 + kq) ^ (l15 & 7)) * 8)];
      __builtin_amdgcn_s_setprio(1);
#pragma unroll
      for (int n = 0; n < 4; ++n) {
        acc[m][n] = __builtin_amdgcn_mfma_f32_16x16x32_bf16(a0, bfr[n][0], acc[m][n], 0, 0, 0);
        acc[m][n] = __builtin_amdgcn_mfma_f32_16x16x32_bf16(a1, bfr[n][1], acc[m][n], 0, 0, 0);
      }
      __builtin_amdgcn_s_setprio(0);
    }
    __builtin_amdgcn_sched_barrier(0);
    asm volatile("s_waitcnt lgkmcnt(0)" ::: "memory");   // my reads done before signaling
    __builtin_amdgcn_sched_barrier(0);
    __builtin_amdgcn_s_barrier();                        // all reads done -> buf reusable
    __builtin_amdgcn_sched_barrier(0);
  }

  // Epilogue: stage 256x256 bf16 tile in smem (exactly 128 KB), chunk-XOR on row&31,
  // then fully-coalesced 16B stores (thread -> consecutive 16B chunks).
  // C fragment layout (m89-verified): col = lane&15, row = (lane>>4)*4 + reg.
#pragma unroll
  for (int m = 0; m < 8; ++m)
#pragma unroll
    for (int n = 0; n < 4; ++n)
#pragma unroll
      for (int r = 0; r < 4; ++r) {
        const int row = wr * 128 + m * 16 + kq * 4 + r;
        const int col = wc * 64 + n * 16 + l15;
        smem[row * 256 + (((col >> 3) ^ (row & 31)) * 8) + (col & 7)] = f2bf(acc[m][n][r]);
      }
  __syncthreads();
  ushort* C = C0 + zc;
#pragma unroll
  for (int j = 0; j < 16; ++j) {
    const int chi = j * 512 + tid;          // 8192 16B-chunks: row = chi>>5, chunk = chi&31
    const int row = chi >> 5, cc = chi & 31;
    *(short8*)&C[(size_t)(bm * 256 + row) * ldc + bn * 256 + cc * 8] =
        *(const short8*)&smem[row * 256 + ((cc ^ (row & 31)) * 8)];
  }
}

// ================= 128x128 2-phase kernel (kept for out-proj split-K) =================
template<bool CSKIP, bool CKB, int EPI, bool ZBH>
__global__ __launch_bounds__(256) void gemm_bt(
    const ushort* __restrict__ A0, long long sAb, long long sAh,
    const ushort* __restrict__ B0, long long sBb, long long sBh,
    void* __restrict__ C0, long long sCb, long long sCh,
    int lda, int ldb, int ldc, int K)
{
  const int bm = blockIdx.x, bn = blockIdx.y, bz = blockIdx.z;
  if (CSKIP && bn > bm) return;
  long long za, zb, zc;
  if (ZBH) {
    const long long bi = bz >> 3, hi = bz & 7;
    za = bi * sAb + hi * sAh; zb = bi * sBb + hi * sBh; zc = bi * sCb + hi * sCh;
  } else {
    za = (long long)bz * sAh; zb = (long long)bz * sBh; zc = (long long)bz * sCh;
  }
  const ushort* A = A0 + za;
  const ushort* B = B0 + zb;
  int kend = K;
  if (CKB) { int kb = (bm + 1) * 128; kend = kb < K ? kb : K; }

  __shared__ ushort smem[16384];

  const int tid = threadIdx.x;
  const int wave = tid >> 6, lane = tid & 63;
  const int wr = wave >> 1, wc = wave & 1;
  const int l15 = lane & 15, kq = lane >> 4;

  const ushort* ag = A + (size_t)(bm * 128 + wave * 16 + (lane >> 2)) * lda + (lane & 3) * 8;
  const ushort* bg = B + (size_t)(bn * 128 + wave * 16 + (lane >> 2)) * ldb + (lane & 3) * 8;
  const size_t aoff = (size_t)64 * lda, boff = (size_t)64 * ldb;

  auto STAGE = [&](int buf, int kk) {
    ushort* al = &smem[buf * 8192 + wave * 16 * 32];
    ushort* bl = al + 4096;
    gl_lds16(ag + kk, al);
    gl_lds16(ag + kk + aoff, al + 64 * 32);
    gl_lds16(bg + kk, bl);
    gl_lds16(bg + kk + boff, bl + 64 * 32);
  };

  f32x4 acc[4][4] = {};
  const int nt = kend >> 5;

  STAGE(0, 0);
  for (int t = 0; t < nt; ++t) {
    const int cur = t & 1;
    if (t + 1 < nt) {
      STAGE(cur ^ 1, (t + 1) << 5);
      asm volatile("s_waitcnt vmcnt(4)" ::: "memory");
    } else {
      asm volatile("s_waitcnt vmcnt(0)" ::: "memory");
    }
    __builtin_amdgcn_s_barrier();
    __builtin_amdgcn_sched_barrier(0);

    const ushort* As = &smem[cur * 8192];
    const ushort* Bs = As + 4096;
    short8 af[4], bfr[4];
#pragma unroll
    for (int m = 0; m < 4; ++m)
      af[m] = *(const short8*)&As[(wr * 64 + m * 16 + l15) * 32 + kq * 8];
#pragma unroll
    for (int n = 0; n < 4; ++n)
      bfr[n] = *(const short8*)&Bs[(wc * 64 + n * 16 + l15) * 32 + kq * 8];
#pragma unroll
    for (int m = 0; m < 4; ++m)
#pragma unroll
      for (int n = 0; n < 4; ++n)
        acc[m][n] = __builtin_amdgcn_mfma_f32_16x16x32_bf16(af[m], bfr[n], acc[m][n], 0, 0, 0);

    __builtin_amdgcn_s_barrier();
    __builtin_amdgcn_sched_barrier(0);
  }

  if constexpr (EPI == 0) {
    ushort* C = (ushort*)C0 + zc;
#pragma unroll
    for (int m = 0; m < 4; ++m)
#pragma unroll
      for (int n = 0; n < 4; ++n)
#pragma unroll
        for (int r = 0; r < 4; ++r)
          smem[csw(wr * 64 + m * 16 + kq * 4 + r, wc * 64 + n * 16 + l15)] = f2bf(acc[m][n][r]);
    __syncthreads();
    const int col = (tid & 15) * 8;
#pragma unroll
    for (int j = 0; j < 8; ++j) {
      const int rr = j * 16 + (tid >> 4);
      *(short8*)&C[(size_t)(bm * 128 + rr) * ldc + bn * 128 + col] =
          *(const short8*)&smem[csw(rr, col)];
    }
  } else {
    float* C = (float*)C0 + zc;
    const int r0 = bm * 128 + wr * 64 + (lane >> 4) * 4;
    const int c0 = bn * 128 + wc * 64 + l15;
#pragma unroll
    for (int m = 0; m < 4; ++m)
#pragma unroll
      for (int n = 0; n < 4; ++n)
#pragma unroll
        for (int r = 0; r < 4; ++r)
          atomicAdd(&C[(size_t)(r0 + m * 16 + r) * ldc + (c0 + n * 16)], acc[m][n][r]);
  }
}

// ---------------- V transpose: QKVg[b_local*1024+s][8192+h*512+d] -> Vtg[bh][d][s] ----------------
__global__ __launch_bounds__(256) void transposeV(const ushort* __restrict__ QKVg,
                                                  ushort* __restrict__ Vtg) {
  __shared__ ushort tile[64][72];
  const int bx = blockIdx.x;
  const int by = blockIdx.y;
  const int bz = blockIdx.z;
  const int b = bz >> 3, h = bz & 7;
  const int t = threadIdx.x;
  const int r = t >> 2, c = (t & 3) * 16;

  const ushort* src = QKVg + (size_t)(b * 1024 + bx * 64 + r) * 12288 + 8192 + h * 512 + by * 64 + c;
  short8 v0 = *(const short8*)src;
  short8 v1 = *(const short8*)(src + 8);
#pragma unroll
  for (int j = 0; j < 8; ++j) { tile[r][c + j] = (ushort)v0[j]; tile[r][c + 8 + j] = (ushort)v1[j]; }
  __syncthreads();

  ushort* dst = Vtg + (size_t)(bz * 512 + by * 64 + r) * 1024 + bx * 64 + c;
  short8 o0, o1;
#pragma unroll
  for (int j = 0; j < 8; ++j) { o0[j] = (short)tile[c + j][r]; o1[j] = (short)tile[c + 8 + j][r]; }
  *(short8*)dst = o0;
  *(short8*)(dst + 8) = o1;
}

// ---------------- causal softmax, one wave per row, in place on bf16 Sg ----------------
__global__ __launch_bounds__(256) void softmax_causal(ushort* __restrict__ S) {
  const int wave = threadIdx.x >> 6, lane = threadIdx.x & 63;
  const size_t row_id = (size_t)blockIdx.x * 4 + wave;
  const int t = (int)(row_id & 1023);
  ushort* row = S + row_id * 1024;
  const int j0 = lane * 16;

  short8 v0 = *(const short8*)&row[j0];
  short8 v1 = *(const short8*)&row[j0 + 8];
  float f[16];
#pragma unroll
  for (int i = 0; i < 8; ++i) { f[i] = bf2f((ushort)v0[i]); f[8 + i] = bf2f((ushort)v1[i]); }

  float m = -1e30f;
#pragma unroll
  for (int i = 0; i < 16; ++i) {
    if (j0 + i > t) f[i] = -1e30f;    // causal mask (covers garbage in skipped tiles too)
    m = fmaxf(m, f[i]);
  }
#pragma unroll
  for (int off = 32; off; off >>= 1) m = fmaxf(m, __shfl_xor(m, off));

  float s = 0.f;
#pragma unroll
  for (int i = 0; i < 16; ++i) { f[i] = __expf(f[i] - m); s += f[i]; }
#pragma unroll
  for (int off = 32; off; off >>= 1) s += __shfl_xor(s, off);
  const float inv = 1.f / s;

#pragma unroll
  for (int i = 0; i < 8; ++i) {
    v0[i] = (short)f2bf(f[i] * inv);
    v1[i] = (short)f2bf(f[8 + i] * inv);
  }
  *(short8*)&row[j0] = v0;
  *(short8*)&row[j0 + 8] = v1;
}

// ---------------- launch ----------------
extern "C" void kernel_launch(void* const* d_in, const int* in_sizes, int n_in,
                              void* d_out, int out_size, void* d_ws, size_t ws_size,
                              hipStream_t stream) {
  const float* x  = (const float*)d_in[0];
  const float* Wq = (const float*)d_in[1];
  const float* Wk = (const float*)d_in[2];
  const float* Wv = (const float*)d_in[3];
  const float* Wo = (const float*)d_in[4];
  float* out = (float*)d_out;

  // group size: largest g whose layout fits ws_size. R(g) = 92,274,688 + g*50,331,648 bytes.
  const int g = (ws_size >= 293601280ull) ? 4 : (ws_size >= 192937984ull) ? 2 : 1;
  const int ng = 8 / g;

  // workspace layout (ushort elements)
  ushort* xb   = (ushort*)d_ws;                       //  8192*512     = 4,194,304
  ushort* Wqkv = xb   + (size_t)4194304;              // 12288*512     = 6,291,456
  ushort* Wob  = Wqkv + (size_t)6291456;              //   512*4096    = 2,097,152
  ushort* AO   = Wob  + (size_t)2097152;              //  8192*4096    = 33,554,432
  ushort* QKVg = AO   + (size_t)33554432;             //  g*1024*12288 = g*12,582,912
  ushort* Vtg  = QKVg + (size_t)g * 12582912;         //  g*8*512*1024 = g*4,194,304
  ushort* Sg   = Vtg  + (size_t)g * 4194304;          //  g*8*1024*1024= g*8,388,608

  const float iscale = (float)(1.0 / pow(512.0, 0.25));   // folded into Wq, Wk

  cvt_f32_bf16<<<2048, 256, 0, stream>>>(x,  xb,             524288, 1.0f);
  cvt_f32_bf16<<<1024, 256, 0, stream>>>(Wq, Wqkv,           262144, iscale);
  cvt_f32_bf16<<<1024, 256, 0, stream>>>(Wk, Wqkv + 2097152, 262144, iscale);
  cvt_f32_bf16<<<1024, 256, 0, stream>>>(Wv, Wqkv + 4194304, 262144, 1.0f);
  cvt_f32_bf16<<<1024, 256, 0, stream>>>(Wo, Wob,            262144, 1.0f);

  for (int grp = 0; grp < ng; ++grp) {
    // QKVg = x[grp] @ Wqkv^T : [g*1024 x 12288], 256^2 tiles
    gemm256<false, false, false><<<dim3(g * 4, 48, 1), 512, 0, stream>>>(
        xb + (size_t)grp * g * 524288, 0, 0,
        Wqkv, 0, 0,
        QKVg, 0, 0,
        512, 512, 12288, 512);

    // V transpose -> Vtg[bh][d][s]
    transposeV<<<dim3(16, 8, 8 * g), 256, 0, stream>>>(QKVg, Vtg);

    // Sg = Q @ K^T per (b,h); causal block skip at 256 granularity
    gemm256<true, false, true><<<dim3(4, 4, 8 * g), 512, 0, stream>>>(
        QKVg,        12582912LL, 512LL,
        QKVg + 4096, 12582912LL, 512LL,
        Sg,          8388608LL,  1048576LL,
        12288, 12288, 1024, 512);

    // causal softmax in place
    softmax_causal<<<g * 2048, 256, 0, stream>>>(Sg);

    // AO[grp] = P @ Vtg^T per (b,h), causal K bound (kend=(bm+1)*256)
    gemm256<false, true, true><<<dim3(4, 2, 8 * g), 512, 0, stream>>>(
        Sg,  8388608LL, 1048576LL,
        Vtg, 4194304LL, 524288LL,
        AO + (size_t)grp * g * 4194304, 4194304LL, 512LL,
        1024, 1024, 4096, 1024);
  }

  // out = AO @ Wo^T, fp32, K split x4 with atomic accumulate (128^2 2-phase kernel)
  zerof4<<<4096, 256, 0, stream>>>((float4*)out, 1048576);
  gemm_bt<false, false, 2, false><<<dim3(64, 4, 4), 256, 0, stream>>>(
      AO,  0, 1024LL,
      Wob, 0, 1024LL,
      out, 0, 0LL,
      4096, 4096, 512, 1024);
}

// Round 7
// 558.750 us; speedup vs baseline: 1.0698x; 1.0698x over previous
//
#include <hip/hip_runtime.h>
#include <hip/hip_bf16.h>
#include <cstdint>
#include <cmath>

// Self-attention, B=8 T=1024 H=8 D=512 (hidden 4096), fp32 in/out, bf16 MFMA compute.
// Big GEMMs (QKV-proj, QK^T, PV, out-proj) on a 256x256/BK=64/8-wave kernel with the
// 8-phase-style schedule: per K-tile 4 quadrant-phases, next-tile staging spread 2
// units/phase in consumption order, counted vmcnt(4) (never 0 mid-loop), XOR-swizzled
// LDS both sides, setprio around MFMA clusters.

typedef __attribute__((ext_vector_type(8))) short short8;
typedef __attribute__((ext_vector_type(4))) float f32x4;

#define DEVINL __device__ __forceinline__

DEVINL float bf2f(ushort u) { union { uint32_t i; float f; } w; w.i = (uint32_t)u << 16; return w.f; }
DEVINL ushort f2bf(float f) {
  union { float f; uint32_t i; } w; w.f = f;
  uint32_t r = w.i + 0x7FFFu + ((w.i >> 16) & 1u);   // RNE
  return (ushort)(r >> 16);
}

DEVINL void gl_lds16(const ushort* g, ushort* l) {
  __builtin_amdgcn_global_load_lds(
      (const __attribute__((address_space(1))) uint32_t*)g,
      (__attribute__((address_space(3))) uint32_t*)l, 16, 0, 0);
}

// ---------------- fp32 -> bf16 convert (8 elems/thread), optional scale ----------------
__global__ __launch_bounds__(256) void cvt_f32_bf16(const float* __restrict__ in,
                                                    ushort* __restrict__ out,
                                                    int n8, float scale) {
  int i = blockIdx.x * 256 + threadIdx.x;
  if (i >= n8) return;
  const float4* p = (const float4*)in + (size_t)i * 2;
  float4 a = p[0], b = p[1];
  short8 o;
  o[0] = (short)f2bf(a.x * scale); o[1] = (short)f2bf(a.y * scale);
  o[2] = (short)f2bf(a.z * scale); o[3] = (short)f2bf(a.w * scale);
  o[4] = (short)f2bf(b.x * scale); o[5] = (short)f2bf(b.y * scale);
  o[6] = (short)f2bf(b.z * scale); o[7] = (short)f2bf(b.w * scale);
  ((short8*)out)[i] = o;
}

// ---------------- zero fp32 buffer ----------------
__global__ __launch_bounds__(256) void zerof4(float4* __restrict__ p, int n4) {
  int i = blockIdx.x * 256 + threadIdx.x;
  if (i < n4) p[i] = float4{0.f, 0.f, 0.f, 0.f};
}

// ================= 256x256 / BK=64 / 8-wave bf16 C = A * B^T, quadrant-phased =================
// A: [M,K] row-major (lda), B: [N,K] row-major (ldb).
// LDS 128 KB: 2 bufs x (A 256x64 | B 256x64). 16B-chunk XOR swizzle: LDS[row][c] holds
// global chunk c^(row&7); staged via inverse-swizzled per-lane GLOBAL source (linear
// gl_lds dest, rule #21), read back with the same XOR -> spread banks.
// Schedule per K-tile t (4 phases, quadrant = (m-half, k-half), 16 MFMA each):
//   ph0: issue next-tile units B0,B1 ; vmcnt(4) ; barrier ; B(ks0)+A(mh0) reads ; MFMA
//   ph1: issue B2,B3 ; vmcnt(4) ; barrier ; A(mh1) reads ; MFMA
//   ph2: issue A0,A2 ; B(ks1)+A(mh0) reads ; MFMA
//   ph3: issue A1,A3 ; A(mh1) reads ; MFMA ; lgkmcnt(0) ; barrier   (buf handoff)
// Consumption order == issue order => vmcnt(4) always suffices; tail tile 2 -> 0.
// CSKIP: skip blocks above causal diagonal. CKB: kend=(bm+1)*256.
// EPI: 0 = bf16 store via LDS-coalesced epilogue; 2 = fp32 atomicAdd (K-split).
// ZBH: blockIdx.z -> (bi=z>>3, hi=z&7) strides; else offset z*s?h.
template<bool CSKIP, bool CKB, int EPI, bool ZBH>
__global__ __launch_bounds__(512, 2) void gemm256(
    const ushort* __restrict__ A0, long long sAb, long long sAh,
    const ushort* __restrict__ B0, long long sBb, long long sBh,
    void* __restrict__ C0, long long sCb, long long sCh,
    int lda, int ldb, int ldc, int K)
{
  const int bm = blockIdx.x, bn = blockIdx.y, bz = blockIdx.z;
  if (CSKIP && bn > bm) return;
  long long za, zb, zc;
  if (ZBH) {
    const long long bi = bz >> 3, hi = bz & 7;
    za = bi * sAb + hi * sAh; zb = bi * sBb + hi * sBh; zc = bi * sCb + hi * sCh;
  } else {
    za = (long long)bz * sAh; zb = (long long)bz * sBh; zc = (long long)bz * sCh;
  }
  const ushort* A = A0 + za;
  const ushort* B = B0 + zb;
  int kend = K;
  if (CKB) { int kb = (bm + 1) * 256; kend = kb < K ? kb : K; }

  __shared__ ushort smem[65536];           // 128 KB: buf*32768; A at +0, B at +16384

  const int tid = threadIdx.x;
  const int wid = tid >> 6, lane = tid & 63;
  const int wr = wid >> 2, wc = wid & 3;   // wave grid 2(M) x 4(N); per-wave C = 128x64
  const int l15 = lane & 15, kq = lane >> 4;

  // staging: one gl_lds per thread covers 8 rows x 64 cols per wave; unit = 64-row band
  const int srow8 = lane >> 3;                       // 0..7
  const int schunk = ((lane & 7) ^ srow8) * 8;       // inverse-swizzled source chunk
  const ushort* ag = A + (size_t)(bm * 256 + wid * 8 + srow8) * lda + schunk;
  const ushort* bg = B + (size_t)(bn * 256 + wid * 8 + srow8) * ldb + schunk;

  auto STA = [&](int buf, int band, int kk) {
    gl_lds16(ag + (size_t)band * 64 * lda + kk, &smem[buf * 32768 + band * 4096 + wid * 512]);
  };
  auto STB = [&](int buf, int band, int kk) {
    gl_lds16(bg + (size_t)band * 64 * ldb + kk, &smem[buf * 32768 + 16384 + band * 4096 + wid * 512]);
  };
  // issue pair p of a K-tile, consumption order: B0,B1 | B2,B3 | A0,A2 | A1,A3
  auto STAGE2 = [&](int buf, int p, int kk) {
    switch (p) {
      case 0: STB(buf, 0, kk); STB(buf, 1, kk); break;
      case 1: STB(buf, 2, kk); STB(buf, 3, kk); break;
      case 2: STA(buf, 0, kk); STA(buf, 2, kk); break;
      default: STA(buf, 1, kk); STA(buf, 3, kk); break;
    }
  };

  f32x4 acc[8][4] = {};
  const int nt = kend >> 6;

#pragma unroll
  for (int p = 0; p < 4; ++p) STAGE2(0, p, 0);       // prologue: tile 0 -> buf 0

  short8 bq[4];                                      // B frags for current k-half
  for (int t = 0; t < nt; ++t) {
    const int cur = t & 1;
    const ushort* As = &smem[cur * 32768];
    const ushort* Bs = As + 16384;
    const bool pre = (t + 1 < nt);
    const int kk1 = (t + 1) << 6;

#pragma unroll
    for (int ph = 0; ph < 4; ++ph) {
      const int mh = ph & 1, ks = ph >> 1;
      if (pre) STAGE2(cur ^ 1, ph, kk1);
      if (ph == 0) {
        if (pre) asm volatile("s_waitcnt vmcnt(4)" ::: "memory");
        else     asm volatile("s_waitcnt vmcnt(2)" ::: "memory");
        __builtin_amdgcn_sched_barrier(0);
        __builtin_amdgcn_s_barrier();
        __builtin_amdgcn_sched_barrier(0);
      } else if (ph == 1) {
        if (pre) asm volatile("s_waitcnt vmcnt(4)" ::: "memory");
        else     asm volatile("s_waitcnt vmcnt(0)" ::: "memory");
        __builtin_amdgcn_sched_barrier(0);
        __builtin_amdgcn_s_barrier();
        __builtin_amdgcn_sched_barrier(0);
      }

      if (mh == 0) {                                 // new k-half: refresh B frags
#pragma unroll
        for (int n = 0; n < 4; ++n)
          bq[n] = *(const short8*)
              &Bs[(wc * 64 + n * 16 + l15) * 64 + (((ks * 4 + kq) ^ (l15 & 7)) * 8)];
      }
      short8 av[4];
#pragma unroll
      for (int m = 0; m < 4; ++m)
        av[m] = *(const short8*)
            &As[(wr * 128 + mh * 64 + m * 16 + l15) * 64 + (((ks * 4 + kq) ^ (l15 & 7)) * 8)];

      __builtin_amdgcn_s_setprio(1);
#pragma unroll
      for (int m = 0; m < 4; ++m)
#pragma unroll
        for (int n = 0; n < 4; ++n)
          acc[mh * 4 + m][n] =
              __builtin_amdgcn_mfma_f32_16x16x32_bf16(av[m], bq[n], acc[mh * 4 + m][n], 0, 0, 0);
      __builtin_amdgcn_s_setprio(0);

      if (ph == 3) {                                 // buf handoff: all reads drained
        asm volatile("s_waitcnt lgkmcnt(0)" ::: "memory");
        __builtin_amdgcn_sched_barrier(0);
        __builtin_amdgcn_s_barrier();
        __builtin_amdgcn_sched_barrier(0);
      }
    }
  }

  // C fragment layout (m89-verified): col = lane&15, row = (lane>>4)*4 + reg
  if constexpr (EPI == 0) {
    // stage 256x256 bf16 tile in smem (exactly 128 KB), chunk-XOR on row&31, coalesced 16B stores
#pragma unroll
    for (int m = 0; m < 8; ++m)
#pragma unroll
      for (int n = 0; n < 4; ++n)
#pragma unroll
        for (int r = 0; r < 4; ++r) {
          const int row = wr * 128 + m * 16 + kq * 4 + r;
          const int col = wc * 64 + n * 16 + l15;
          smem[row * 256 + (((col >> 3) ^ (row & 31)) * 8) + (col & 7)] = f2bf(acc[m][n][r]);
        }
    __syncthreads();
    ushort* C = (ushort*)C0 + zc;
#pragma unroll
    for (int j = 0; j < 16; ++j) {
      const int chi = j * 512 + tid;
      const int row = chi >> 5, cc = chi & 31;
      *(short8*)&C[(size_t)(bm * 256 + row) * ldc + bn * 256 + cc * 8] =
          *(const short8*)&smem[row * 256 + ((cc ^ (row & 31)) * 8)];
    }
  } else {
    float* C = (float*)C0 + zc;
#pragma unroll
    for (int m = 0; m < 8; ++m)
#pragma unroll
      for (int n = 0; n < 4; ++n)
#pragma unroll
        for (int r = 0; r < 4; ++r)
          atomicAdd(&C[(size_t)(bm * 256 + wr * 128 + m * 16 + kq * 4 + r) * ldc
                       + bn * 256 + wc * 64 + n * 16 + l15], acc[m][n][r]);
  }
}

// ---------------- V transpose: QKVg[b_local*1024+s][8192+h*512+d] -> Vtg[bh][d][s] ----------------
__global__ __launch_bounds__(256) void transposeV(const ushort* __restrict__ QKVg,
                                                  ushort* __restrict__ Vtg) {
  __shared__ ushort tile[64][72];
  const int bx = blockIdx.x;
  const int by = blockIdx.y;
  const int bz = blockIdx.z;
  const int b = bz >> 3, h = bz & 7;
  const int t = threadIdx.x;
  const int r = t >> 2, c = (t & 3) * 16;

  const ushort* src = QKVg + (size_t)(b * 1024 + bx * 64 + r) * 12288 + 8192 + h * 512 + by * 64 + c;
  short8 v0 = *(const short8*)src;
  short8 v1 = *(const short8*)(src + 8);
#pragma unroll
  for (int j = 0; j < 8; ++j) { tile[r][c + j] = (ushort)v0[j]; tile[r][c + 8 + j] = (ushort)v1[j]; }
  __syncthreads();

  ushort* dst = Vtg + (size_t)(bz * 512 + by * 64 + r) * 1024 + bx * 64 + c;
  short8 o0, o1;
#pragma unroll
  for (int j = 0; j < 8; ++j) { o0[j] = (short)tile[c + j][r]; o1[j] = (short)tile[c + 8 + j][r]; }
  *(short8*)dst = o0;
  *(short8*)(dst + 8) = o1;
}

// ---------------- causal softmax, one wave per row, in place on bf16 Sg ----------------
__global__ __launch_bounds__(256) void softmax_causal(ushort* __restrict__ S) {
  const int wave = threadIdx.x >> 6, lane = threadIdx.x & 63;
  const size_t row_id = (size_t)blockIdx.x * 4 + wave;
  const int t = (int)(row_id & 1023);
  ushort* row = S + row_id * 1024;
  const int j0 = lane * 16;

  short8 v0 = *(const short8*)&row[j0];
  short8 v1 = *(const short8*)&row[j0 + 8];
  float f[16];
#pragma unroll
  for (int i = 0; i < 8; ++i) { f[i] = bf2f((ushort)v0[i]); f[8 + i] = bf2f((ushort)v1[i]); }

  float m = -1e30f;
#pragma unroll
  for (int i = 0; i < 16; ++i) {
    if (j0 + i > t) f[i] = -1e30f;    // causal mask (covers garbage in skipped tiles too)
    m = fmaxf(m, f[i]);
  }
#pragma unroll
  for (int off = 32; off; off >>= 1) m = fmaxf(m, __shfl_xor(m, off));

  float s = 0.f;
#pragma unroll
  for (int i = 0; i < 16; ++i) { f[i] = __expf(f[i] - m); s += f[i]; }
#pragma unroll
  for (int off = 32; off; off >>= 1) s += __shfl_xor(s, off);
  const float inv = 1.f / s;

#pragma unroll
  for (int i = 0; i < 8; ++i) {
    v0[i] = (short)f2bf(f[i] * inv);
    v1[i] = (short)f2bf(f[8 + i] * inv);
  }
  *(short8*)&row[j0] = v0;
  *(short8*)&row[j0 + 8] = v1;
}

// ---------------- launch ----------------
extern "C" void kernel_launch(void* const* d_in, const int* in_sizes, int n_in,
                              void* d_out, int out_size, void* d_ws, size_t ws_size,
                              hipStream_t stream) {
  const float* x  = (const float*)d_in[0];
  const float* Wq = (const float*)d_in[1];
  const float* Wk = (const float*)d_in[2];
  const float* Wv = (const float*)d_in[3];
  const float* Wo = (const float*)d_in[4];
  float* out = (float*)d_out;

  // group size: largest g whose layout fits ws_size. R(g) = 92,274,688 + g*50,331,648 bytes.
  const int g = (ws_size >= 293601280ull) ? 4 : (ws_size >= 192937984ull) ? 2 : 1;
  const int ng = 8 / g;

  // workspace layout (ushort elements)
  ushort* xb   = (ushort*)d_ws;                       //  8192*512     = 4,194,304
  ushort* Wqkv = xb   + (size_t)4194304;              // 12288*512     = 6,291,456
  ushort* Wob  = Wqkv + (size_t)6291456;              //   512*4096    = 2,097,152
  ushort* AO   = Wob  + (size_t)2097152;              //  8192*4096    = 33,554,432
  ushort* QKVg = AO   + (size_t)33554432;             //  g*1024*12288 = g*12,582,912
  ushort* Vtg  = QKVg + (size_t)g * 12582912;         //  g*8*512*1024 = g*4,194,304
  ushort* Sg   = Vtg  + (size_t)g * 4194304;          //  g*8*1024*1024= g*8,388,608

  const float iscale = (float)(1.0 / pow(512.0, 0.25));   // folded into Wq, Wk

  cvt_f32_bf16<<<2048, 256, 0, stream>>>(x,  xb,             524288, 1.0f);
  cvt_f32_bf16<<<1024, 256, 0, stream>>>(Wq, Wqkv,           262144, iscale);
  cvt_f32_bf16<<<1024, 256, 0, stream>>>(Wk, Wqkv + 2097152, 262144, iscale);
  cvt_f32_bf16<<<1024, 256, 0, stream>>>(Wv, Wqkv + 4194304, 262144, 1.0f);
  cvt_f32_bf16<<<1024, 256, 0, stream>>>(Wo, Wob,            262144, 1.0f);

  for (int grp = 0; grp < ng; ++grp) {
    // QKVg = x[grp] @ Wqkv^T : [g*1024 x 12288]
    gemm256<false, false, 0, false><<<dim3(g * 4, 48, 1), 512, 0, stream>>>(
        xb + (size_t)grp * g * 524288, 0, 0,
        Wqkv, 0, 0,
        QKVg, 0, 0,
        512, 512, 12288, 512);

    // V transpose -> Vtg[bh][d][s]
    transposeV<<<dim3(16, 8, 8 * g), 256, 0, stream>>>(QKVg, Vtg);

    // Sg = Q @ K^T per (b,h); causal block skip at 256 granularity
    gemm256<true, false, 0, true><<<dim3(4, 4, 8 * g), 512, 0, stream>>>(
        QKVg,        12582912LL, 512LL,
        QKVg + 4096, 12582912LL, 512LL,
        Sg,          8388608LL,  1048576LL,
        12288, 12288, 1024, 512);

    // causal softmax in place
    softmax_causal<<<g * 2048, 256, 0, stream>>>(Sg);

    // AO[grp] = P @ Vtg^T per (b,h), causal K bound (kend=(bm+1)*256)
    gemm256<false, true, 0, true><<<dim3(4, 2, 8 * g), 512, 0, stream>>>(
        Sg,  8388608LL, 1048576LL,
        Vtg, 4194304LL, 524288LL,
        AO + (size_t)grp * g * 4194304, 4194304LL, 512LL,
        1024, 1024, 4096, 1024);
  }

  // out = AO @ Wo^T, fp32, K split x4 (z) with atomic accumulate
  zerof4<<<4096, 256, 0, stream>>>((float4*)out, 1048576);
  gemm256<false, false, 2, false><<<dim3(32, 2, 4), 512, 0, stream>>>(
      AO,  0, 1024LL,
      Wob, 0, 1024LL,
      out, 0, 0LL,
      4096, 4096, 512, 1024);
}